// Round 13
// baseline (391.604 us; speedup 1.0000x reference)
//
#include <hip/hip_runtime.h>
#include <math.h>

#define NPTS 4096
#define BLK 128
#define V 64
#define NPROJ 256
#define NBATCH 32

// R13: 8 KB LDS per sort-wave (was 16 KB) -> ~16 resident waves/CU (was ~7).
// Basis: A<->B trips (m512/m1024/m2048) preserve idx[11] (=lane bit 5), so
// the permutation is closed over lane halves; each trip runs in a 512-slot
// (8 KB) sub-buffer, halves serialized under exec masks (same-wave DS is
// in-order -> no barriers, read returns pre-write data for the WAR pair).
// m4096's reversal flips idx[11] (cross-half), so the block's two 8 KB
// buffers combine: the wave pair serializes m4096 through the shared 16 KB
// (2 barriers; idle hidden by other blocks). m4096 code = R8's verified
// full-buffer sequence, unchanged.
// Layouts (element idx, 12 bits):
//   A: T=idx[11:6], c=idx[5:2]                (regs = idx[5:0])
//   B: T={idx[11:10],idx[5:2]}, c=idx[9:6]    (regs = {idx[9:6],idx[1:0]})
//   C: T=idx[9:4],  c={idx[11:10],idx[3:2]}   (regs = {idx[11:10],idx[3:0]})
// Full-buffer slot: A/B: (T<<4)|(c^(T&15)); C: (T<<4)|(c^(T>>2&15)).
// Half-buffer slot (drop bit 9 = idx[11]): write (((t>>4)&1)<<8)|(c<<4)|(t15^c),
// read ((t&31)<<4)|(c^t15). Bank profile unchanged (bit 9 not a bank bit).

__device__ __forceinline__ void cmpex_asc(float& a, float& b) {
    const float lo = fminf(a, b), hi = fmaxf(a, b);
    a = lo; b = hi;
}

template<int JB, int JL>
__device__ __forceinline__ void stages(float* v) {
#pragma unroll
    for (int r = 0; r < V; ++r)
        if ((r & JB) == 0) cmpex_asc(v[r], v[r | JB]);
    if constexpr (JB > JL) stages<(JB >> 1), JL>(v);
}

template<int JB>
__device__ __forceinline__ void stage1(float* v) {
#pragma unroll
    for (int r = 0; r < V; ++r)
        if ((r & JB) == 0) cmpex_asc(v[r], v[r | JB]);
}

template<int MASK>
__device__ __forceinline__ void rev_inreg(float* v) {
    constexpr int S = (MASK + 1) >> 1;
#pragma unroll
    for (int r = 0; r < V; ++r) {
        if ((r & S) == 0) {
            const float a = v[r], b = v[r ^ MASK];
            v[r] = fminf(a, b);
            v[r ^ MASK] = fmaxf(a, b);
        }
    }
}

template<int XM>
__device__ __forceinline__ void rev_shfl(float* v, bool hi) {
#pragma unroll
    for (int r = 0; r < 32; ++r) {
        const float pa = __shfl_xor(v[63 - r], XM, 64);
        const float pb = __shfl_xor(v[r], XM, 64);
        v[r]      = hi ? fmaxf(v[r], pa)      : fminf(v[r], pa);
        v[63 - r] = hi ? fmaxf(v[63 - r], pb) : fminf(v[63 - r], pb);
    }
}
template<int XM>
__device__ __forceinline__ void stage_shfl(float* v, bool hi) {
#pragma unroll
    for (int r = 0; r < V; ++r) {
        const float q = __shfl_xor(v[r], XM, 64);
        v[r] = hi ? fmaxf(v[r], q) : fminf(v[r], q);
    }
}

// ---- half-buffer (512-slot) trip helpers; active lanes only ----
__device__ __forceinline__ void write_AB_h(float4* s4, const float* v, int t) {
    const int t15 = t & 15;
    const int base = ((t >> 4) & 1) << 8;
#pragma unroll
    for (int c = 0; c < 16; ++c)
        s4[base | (c << 4) | (t15 ^ c)] =
            make_float4(v[4*c], v[4*c+1], v[4*c+2], v[4*c+3]);
}
__device__ __forceinline__ void read_own_h(const float4* s4, float* v, int t) {
    const int t15 = t & 15;
    const int base = (t & 31) << 4;
#pragma unroll
    for (int c = 0; c < 16; ++c) {
        const float4 f = s4[base | (c ^ t15)];
        v[4*c] = f.x; v[4*c+1] = f.y; v[4*c+2] = f.z; v[4*c+3] = f.w;
    }
}
__device__ __forceinline__ void read_rev_h(const float4* s4, float* v, int t,
                                           int PM, int CM, int KB, int TB) {
    const int t15 = t & 15;
    const int ob = (t & 31) << 4;
    const int pt = t ^ PM;
    const int pb = (pt & 31) << 4, pt15 = pt & 15;
    const int tb = t & TB;
#pragma unroll
    for (int c = 0; c < 16; ++c) {
        const float4 o = s4[ob | (c ^ t15)];
        const float4 q = s4[pb | ((c ^ CM) ^ pt15)];
        const bool mx = ((c & KB) | tb) != 0;
        v[4*c+0] = mx ? fmaxf(o.x, q.w) : fminf(o.x, q.w);
        v[4*c+1] = mx ? fmaxf(o.y, q.z) : fminf(o.y, q.z);
        v[4*c+2] = mx ? fmaxf(o.z, q.y) : fminf(o.z, q.y);
        v[4*c+3] = mx ? fmaxf(o.w, q.x) : fminf(o.w, q.x);
    }
}

// ---- full-buffer (1024-slot) helpers for m4096 / publish (R8-verified) ----
__device__ __forceinline__ void write_AB_f(float4* s4, const float* v, int t) {
    const int t15 = t & 15;
    const int sAB = (t >> 4) << 8;
#pragma unroll
    for (int c = 0; c < 16; ++c)
        s4[sAB | (c << 4) | (t15 ^ c)] =
            make_float4(v[4*c], v[4*c+1], v[4*c+2], v[4*c+3]);
}
__device__ __forceinline__ void write_own_f(float4* s4, const float* v, int t) {
    const int t15 = t & 15;
#pragma unroll
    for (int c = 0; c < 16; ++c)
        s4[(t << 4) | (c ^ t15)] =
            make_float4(v[4*c], v[4*c+1], v[4*c+2], v[4*c+3]);
}
__device__ __forceinline__ void read_own_f(const float4* s4, float* v, int t) {
    const int t15 = t & 15;
#pragma unroll
    for (int c = 0; c < 16; ++c) {
        const float4 f = s4[(t << 4) | (c ^ t15)];
        v[4*c] = f.x; v[4*c+1] = f.y; v[4*c+2] = f.z; v[4*c+3] = f.w;
    }
}
__device__ __forceinline__ void write_AC_f(float4* s4, const float* v, int t) {
    const int t15 = t & 15;
    const int qAC = ((t >> 4) << 2) ^ t15;
#pragma unroll
    for (int c = 0; c < 16; ++c)
        s4[(t15 << 6) | ((c >> 2) << 4) | (qAC ^ (c & 3))] =
            make_float4(v[4*c], v[4*c+1], v[4*c+2], v[4*c+3]);
}
__device__ __forceinline__ void read_rev_C_f(const float4* s4, float* v, int t) {
    const int th = (t >> 2) & 15;
    const int pt = t ^ 63, pth = th ^ 15;
#pragma unroll
    for (int c = 0; c < 16; ++c) {
        const float4 o = s4[(t << 4) | (c ^ th)];
        const float4 q = s4[(pt << 4) | ((c ^ 15) ^ pth)];
        const bool mx = (c & 8) != 0;
        v[4*c+0] = mx ? fmaxf(o.x, q.w) : fminf(o.x, q.w);
        v[4*c+1] = mx ? fmaxf(o.y, q.z) : fminf(o.y, q.z);
        v[4*c+2] = mx ? fmaxf(o.z, q.y) : fminf(o.z, q.y);
        v[4*c+3] = mx ? fmaxf(o.w, q.x) : fminf(o.w, q.x);
    }
}
__device__ __forceinline__ void write_CB_f(float4* s4, const float* v, int t) {
    const int sCB = (t & 3) << 6;
    const int qCB = (t >> 2) ^ ((t & 3) << 2);
#pragma unroll
    for (int c = 0; c < 16; ++c)
        s4[((c >> 2) << 8) | sCB | ((c & 3) << 4) | (qCB ^ (c & 3))] =
            make_float4(v[4*c], v[4*c+1], v[4*c+2], v[4*c+3]);
}

__device__ __forceinline__ void load_project(const float* base, float* v,
                                             float p0, float p1, float p2) {
    const float4* b4 = (const float4*)base;
#pragma unroll
    for (int g = 0; g < 16; ++g) {
        float4 a = b4[g * 3 + 0], c = b4[g * 3 + 1], d = b4[g * 3 + 2];
        v[4*g+0] = a.x * p0 + a.y * p1 + a.z * p2;
        v[4*g+1] = a.w * p0 + c.x * p1 + c.y * p2;
        v[4*g+2] = c.z * p0 + c.w * p1 + d.x * p2;
        v[4*g+3] = d.y * p0 + d.z * p1 + d.w * p2;
    }
}

__global__ __launch_bounds__(BLK, 3) void swd_kernel(
    const float* __restrict__ x, const float* __restrict__ y,
    const float* __restrict__ theta, const float* __restrict__ rot,
    float* __restrict__ per_batch) {
    __shared__ float4 pairbuf[1024];   // 16 KB: two 512-slot halves

    const int t = threadIdx.x & 63;    // wave lane
    const int w = threadIdx.x >> 6;    // 0: x-wave, 1: y-wave
    const int p = blockIdx.x;
    const int b = blockIdx.y;

    const float t0 = theta[p * 3 + 0], t1 = theta[p * 3 + 1], t2 = theta[p * 3 + 2];
    const float* R = rot + b * 9;
    const float p0 = t0 * R[0] + t1 * R[3] + t2 * R[6];
    const float p1 = t0 * R[1] + t1 * R[4] + t2 * R[7];
    const float p2 = t0 * R[2] + t1 * R[5] + t2 * R[8];

    float4* sub = pairbuf + (w << 9);  // this wave's private 8 KB
    const float* src = w ? y : x;

    float v[V];
    load_project(src + (size_t)b * NPTS * 3 + (size_t)t * V * 3, v, p0, p1, p2);

    const bool h1 = (t & 1) != 0;
    const bool h2 = (t & 2) != 0;

    // ---- in-reg merges 2..64 ----
    rev_inreg<1>(v);
    rev_inreg<3>(v);  stages<1, 1>(v);
    rev_inreg<7>(v);  stages<2, 1>(v);
    rev_inreg<15>(v); stages<4, 1>(v);
    rev_inreg<31>(v); stages<8, 1>(v);
    rev_inreg<63>(v); stages<16, 1>(v);
    // ---- m128, m256 via lane shuffles (masks 1,2,3) ----
    rev_shfl<1>(v, h1);
    stages<32, 1>(v);
    rev_shfl<3>(v, h2);
    stage_shfl<2>(v, h2); stage_shfl<1>(v, h1);
    stages<32, 1>(v);

    // ---- m512, m1024, m2048: half-split 8 KB trips (barrier-free) ----
#pragma unroll 1
    for (int mi = 0; mi < 3; ++mi) {
        const int PM = (mi == 2) ? 31 : 15;
        const int CM = (mi == 0) ? 7 : 15;
        const int KB = (mi == 0) ? 4 : (mi == 1) ? 8 : 0;
        const int TB = (mi == 2) ? 16 : 0;
        // reversal trip, halves serialized (same-wave DS is in-order)
        if (t < 32)  write_AB_h(sub, v, t);
        if (t < 32)  read_rev_h(sub, v, t, PM, CM, KB, TB);
        if (t >= 32) write_AB_h(sub, v, t);
        if (t >= 32) read_rev_h(sub, v, t, PM, CM, KB, TB);
        // B-resident cleaners
        if (mi >= 2) stage1<32>(v);
        if (mi >= 1) stage1<16>(v);
        stage1<8>(v); stage1<4>(v);
        // return trip
        if (t < 32)  write_AB_h(sub, v, t);
        if (t < 32)  read_own_h(sub, v, t);
        if (t >= 32) write_AB_h(sub, v, t);
        if (t >= 32) read_own_h(sub, v, t);
        // A-resident tail
        stages<32, 1>(v);
    }

    // ---- m4096: pair-shared 16 KB, waves serialized ----
#pragma unroll 1
    for (int who = 0; who < 2; ++who) {
        __syncthreads();
        if (w == who) {
            write_AC_f(pairbuf, v, t);
            read_rev_C_f(pairbuf, v, t);
            stage1<16>(v);                       // j=1024 (C)
            write_CB_f(pairbuf, v, t);
            read_own_f(pairbuf, v, t);
            stage1<32>(v); stage1<16>(v);        // j=512,256 (B)
            stage1<8>(v);  stage1<4>(v);         // j=128,64  (B)
            write_AB_f(pairbuf, v, t);
            read_own_f(pairbuf, v, t);
            stages<32, 1>(v);                    // tail (A)
            if (w == 1) write_own_f(pairbuf, v, t);  // publish sorted y
        }
    }
    __syncthreads();

    if (w == 0) {
        float yv[V];
        read_own_f(pairbuf, yv, t);
        float s = 0.0f;
#pragma unroll
        for (int r = 0; r < V; ++r) {
            const float d = v[r] - yv[r];
            s += d * d;
        }
        for (int off = 32; off > 0; off >>= 1) s += __shfl_down(s, off, 64);
        if (t == 0) atomicAdd(&per_batch[b], s);
    }
}

__global__ void finalize_kernel(const float* __restrict__ per_batch, float* __restrict__ out) {
    const int t = threadIdx.x;  // 64 threads
    float v = (t < NBATCH) ? sqrtf(per_batch[t] * (1.0f / (float)NPROJ)) : 0.0f;
    for (int off = 32; off > 0; off >>= 1) v += __shfl_down(v, off, 64);
    if (t == 0) out[0] = v * (1.0f / (float)NBATCH);
}

extern "C" void kernel_launch(void* const* d_in, const int* in_sizes, int n_in,
                              void* d_out, int out_size, void* d_ws, size_t ws_size,
                              hipStream_t stream) {
    const float* x = (const float*)d_in[0];
    const float* y = (const float*)d_in[1];
    const float* theta = (const float*)d_in[2];
    const float* rot = (const float*)d_in[3];
    float* per_batch = (float*)d_ws;
    float* out = (float*)d_out;

    hipMemsetAsync(per_batch, 0, NBATCH * sizeof(float), stream);

    dim3 grid(NPROJ, NBATCH);
    swd_kernel<<<grid, BLK, 0, stream>>>(x, y, theta, rot, per_batch);

    finalize_kernel<<<1, 64, 0, stream>>>(per_batch, out);
}